// Round 1
// baseline (526.589 us; speedup 1.0000x reference)
//
#include <hip/hip_runtime.h>
#include <hip/hip_bf16.h>

#define Bn 2
#define Cn 512
#define Hn 256
#define Wn 256
#define EPSc 1e-5f

// ---------------- K1: fused dual depthwise reduction ----------------
// block = 256 threads (4 waves), grid = B*C = 1024 blocks; one (b,c) slab each.
// wave j handles rows h = j, j+4, ...  lane l covers columns 4l..4l+3.
// s1[bc][w] = sum_h x[h][w]*w1[c][h]   (per-lane float4 accumulator, combined via LDS)
// s2[bc][h] = sum_w x[h][w]*w2[c][w]   (butterfly reduce per row)
__global__ __launch_bounds__(256) void k1_reduce(const float* __restrict__ x,
                                                 const float* __restrict__ w1,
                                                 const float* __restrict__ w2,
                                                 float* __restrict__ s1,
                                                 float* __restrict__ s2) {
    const int bc   = blockIdx.x;           // b*512 + c
    const int c    = bc & (Cn - 1);
    const int tid  = threadIdx.x;
    const int wave = tid >> 6;
    const int lane = tid & 63;
    const float* __restrict__ xs = x + (size_t)bc * (Hn * Wn);

    __shared__ float w1s[Hn];
    __shared__ float s1buf[4][Wn];

    w1s[tid] = w1[c * Hn + tid];
    __syncthreads();

    const float4 w2v = *(const float4*)(w2 + c * Wn + lane * 4);

    float4 acc = make_float4(0.f, 0.f, 0.f, 0.f);
    #pragma unroll 2
    for (int h = wave; h < Hn; h += 4) {
        float4 v = *(const float4*)(xs + h * Wn + lane * 4);
        float wh = w1s[h];
        acc.x += v.x * wh; acc.y += v.y * wh;
        acc.z += v.z * wh; acc.w += v.w * wh;
        float p = v.x * w2v.x + v.y * w2v.y + v.z * w2v.z + v.w * w2v.w;
        #pragma unroll
        for (int off = 32; off; off >>= 1) p += __shfl_xor(p, off, 64);
        if (lane == 0) s2[bc * Hn + h] = p;
    }
    ((float4*)(&s1buf[wave][0]))[lane] = acc;
    __syncthreads();
    s1[bc * Wn + tid] = s1buf[0][tid] + s1buf[1][tid] + s1buf[2][tid] + s1buf[3][tid];
}

// ---------------- K2: per-channel BN(train) + ReLU + dot ----------------
// one wave per channel; 512 values per tensor per channel (b in {0,1} x 256).
// writes numv[c*2+b]  (== dot_cb flattened, == reference reshape order)
__global__ __launch_bounds__(256) void k2_bn_dot(const float* __restrict__ s1,
                                                 const float* __restrict__ s2,
                                                 const float* __restrict__ g1,
                                                 const float* __restrict__ b1,
                                                 const float* __restrict__ g2,
                                                 const float* __restrict__ b2,
                                                 float* __restrict__ numv) {
    const int c = blockIdx.x * 4 + (threadIdx.x >> 6);
    const int lane = threadIdx.x & 63;
    if (c >= Cn) return;

    float v1[2][4], v2[2][4];
    float sum1 = 0.f, sq1 = 0.f, sum2 = 0.f, sq2 = 0.f;
    #pragma unroll
    for (int b = 0; b < 2; b++) {
        #pragma unroll
        for (int m = 0; m < 4; m++) {
            float a = s1[(b * Cn + c) * Wn + lane + 64 * m];
            float d = s2[(b * Cn + c) * Hn + lane + 64 * m];
            v1[b][m] = a; v2[b][m] = d;
            sum1 += a; sq1 += a * a;
            sum2 += d; sq2 += d * d;
        }
    }
    #pragma unroll
    for (int off = 32; off; off >>= 1) {
        sum1 += __shfl_xor(sum1, off, 64);
        sq1  += __shfl_xor(sq1,  off, 64);
        sum2 += __shfl_xor(sum2, off, 64);
        sq2  += __shfl_xor(sq2,  off, 64);
    }
    const float inv = 1.0f / 512.0f;
    float m1 = sum1 * inv, m2 = sum2 * inv;
    float r1 = rsqrtf(sq1 * inv - m1 * m1 + EPSc);
    float r2 = rsqrtf(sq2 * inv - m2 * m2 + EPSc);
    float G1 = g1[c], B1 = b1[c], G2 = g2[c], B2 = b2[c];

    #pragma unroll
    for (int b = 0; b < 2; b++) {
        float d = 0.f;
        #pragma unroll
        for (int m = 0; m < 4; m++) {
            float a = fmaxf((v1[b][m] - m1) * r1 * G1 + B1, 0.f);
            float e = fmaxf((v2[b][m] - m2) * r2 * G2 + B2, 0.f);
            d += a * e;
        }
        #pragma unroll
        for (int off = 32; off; off >>= 1) d += __shfl_xor(d, off, 64);
        if (lane == 0) numv[c * 2 + b] = d;
    }
}

// ---------------- K3: fc1  h1[bb,j] = numv[bb,:]·lw1[j,:] + lb1[j] ----------------
// one wave per output, 2048 outputs -> 512 blocks
__global__ __launch_bounds__(256) void k3_fc1(const float* __restrict__ numv,
                                              const float* __restrict__ lw1,
                                              const float* __restrict__ lb1,
                                              float* __restrict__ h1) {
    const int wid  = blockIdx.x * 4 + (threadIdx.x >> 6);  // 0..2047
    const int lane = threadIdx.x & 63;
    const int bb = wid >> 10, j = wid & 1023;
    const float* __restrict__ row = lw1 + (size_t)j * Cn;
    const float* __restrict__ nv  = numv + bb * Cn;
    float p = 0.f;
    #pragma unroll
    for (int m = 0; m < 2; m++) {
        float4 a = *(const float4*)(row + lane * 4 + m * 256);
        float4 n = *(const float4*)(nv  + lane * 4 + m * 256);
        p += a.x * n.x + a.y * n.y + a.z * n.z + a.w * n.w;
    }
    #pragma unroll
    for (int off = 32; off; off >>= 1) p += __shfl_xor(p, off, 64);
    if (lane == 0) h1[bb * 1024 + j] = p + lb1[j];
}

// ---------------- K4: fc2  h2[bb,c] = h1[bb,:]·lw2[c,:] + lb2[c] ----------------
// one wave per output, 1024 outputs -> 256 blocks
__global__ __launch_bounds__(256) void k4_fc2(const float* __restrict__ h1,
                                              const float* __restrict__ lw2,
                                              const float* __restrict__ lb2,
                                              float* __restrict__ h2) {
    const int wid  = blockIdx.x * 4 + (threadIdx.x >> 6);  // 0..1023
    const int lane = threadIdx.x & 63;
    const int bb = wid >> 9, c = wid & 511;
    const float* __restrict__ row = lw2 + (size_t)c * 1024;
    const float* __restrict__ hv  = h1 + bb * 1024;
    float p = 0.f;
    #pragma unroll
    for (int m = 0; m < 4; m++) {
        float4 a = *(const float4*)(row + lane * 4 + m * 256);
        float4 n = *(const float4*)(hv  + lane * 4 + m * 256);
        p += a.x * n.x + a.y * n.y + a.z * n.z + a.w * n.w;
    }
    #pragma unroll
    for (int off = 32; off; off >>= 1) p += __shfl_xor(p, off, 64);
    if (lane == 0) h2[bb * Cn + c] = p + lb2[c];
}

// ---------------- K5: softmax over axis=1 (512), 2 blocks ----------------
__global__ __launch_bounds__(512) void k5_softmax(const float* __restrict__ h2,
                                                  float* __restrict__ scale) {
    __shared__ float red[512];
    const int bb = blockIdx.x, t = threadIdx.x;
    float v = h2[bb * Cn + t];
    red[t] = v;
    __syncthreads();
    for (int s = 256; s; s >>= 1) {
        if (t < s) red[t] = fmaxf(red[t], red[t + s]);
        __syncthreads();
    }
    float mx = red[0];
    __syncthreads();
    float e = expf(v - mx);
    red[t] = e;
    __syncthreads();
    for (int s = 256; s; s >>= 1) {
        if (t < s) red[t] += red[t + s];
        __syncthreads();
    }
    scale[bb * Cn + t] = e / red[0];
}

// ---------------- K6: out = x * scale[b*512+c] ----------------
__global__ __launch_bounds__(256) void k6_scale(const float* __restrict__ x,
                                                const float* __restrict__ scale,
                                                float* __restrict__ out, int n4) {
    int i = blockIdx.x * 256 + threadIdx.x;
    const int stride = gridDim.x * 256;
    for (; i < n4; i += stride) {
        float4 v = ((const float4*)x)[i];
        float s = scale[i >> 14];   // (i*4)/65536 -> slab index b*512+c
        ((float4*)out)[i] = make_float4(v.x * s, v.y * s, v.z * s, v.w * s);
    }
}

extern "C" void kernel_launch(void* const* d_in, const int* in_sizes, int n_in,
                              void* d_out, int out_size, void* d_ws, size_t ws_size,
                              hipStream_t stream) {
    const float* x   = (const float*)d_in[0];
    const float* w1  = (const float*)d_in[1];
    const float* w2  = (const float*)d_in[2];
    const float* g1  = (const float*)d_in[3];
    const float* b1  = (const float*)d_in[4];
    const float* g2  = (const float*)d_in[5];
    const float* b2  = (const float*)d_in[6];
    const float* lw1 = (const float*)d_in[7];
    const float* lb1 = (const float*)d_in[8];
    const float* lw2 = (const float*)d_in[9];
    const float* lb2 = (const float*)d_in[10];
    float* out = (float*)d_out;

    float* ws   = (float*)d_ws;
    float* s1   = ws;                       // [B,C,W]  262144
    float* s2   = ws + 262144;              // [B,C,H]  262144
    float* numv = ws + 524288;              // [1024]
    float* h1   = ws + 525312;              // [2,1024]
    float* h2   = ws + 527360;              // [2,512]
    float* scl  = ws + 528384;              // [2,512]

    k1_reduce<<<Bn * Cn, 256, 0, stream>>>(x, w1, w2, s1, s2);
    k2_bn_dot<<<Cn / 4, 256, 0, stream>>>(s1, s2, g1, b1, g2, b2, numv);
    k3_fc1<<<512, 256, 0, stream>>>(numv, lw1, lb1, h1);
    k4_fc2<<<256, 256, 0, stream>>>(h1, lw2, lb2, h2);
    k5_softmax<<<Bn, 512, 0, stream>>>(h2, scl);

    const int n4 = (Bn * Cn * Hn * Wn) / 4;  // 16,777,216
    k6_scale<<<4096, 256, 0, stream>>>(x, scl, out, n4);
}